// Round 1
// baseline (554.477 us; speedup 1.0000x reference)
//
#include <hip/hip_runtime.h>

// FlashQwenAttention: x@wq/wk/wv -> rmsnorm(q,k) -> rope -> GQA causal attn -> ctx@wo
// B=2 S=1024 H=4096 NH=32 NKV=8 HD=128. Inputs fp32; internal bf16 MFMA.
// R6: replace 128^2 m97-style gemm_bt with 256^2 8-phase counted-vmcnt GEMM
// (T1 XCD swizzle + T2 3-bit LDS XOR swizzle + T3/T4 phase pipeline + T5 setprio).
// 2 dbuf slots x (A[256][64] + B[256][64]) bf16 = 128 KiB LDS, 8 waves (2Mx4N),
// quarter-tile staging 2-5 phases ahead; vmcnt(4) steady, drain 4->2->0.

#define NH_ 32
#define NKV_ 8
#define HD_ 128
#define SEQ_ 1024
#define HID_ 4096
#define NQKV_ 6144

typedef unsigned short u16;
typedef __bf16 bf16x8 __attribute__((ext_vector_type(8)));
typedef float f32x4 __attribute__((ext_vector_type(4)));

__device__ __forceinline__ u16 f2bf(float f) {
  unsigned int u = __float_as_uint(f);
  return (u16)((u + 0x7FFFu + ((u >> 16) & 1u)) >> 16);
}
__device__ __forceinline__ float bf2f(u16 u) {
  return __uint_as_float(((unsigned int)u) << 16);
}
__device__ __forceinline__ f32x4 mfma16(bf16x8 a, bf16x8 b, f32x4 c) {
  return __builtin_amdgcn_mfma_f32_16x16x32_bf16(a, b, c, 0, 0, 0);
}
__device__ __forceinline__ void gld16(u16* lds, const u16* g) {
  __builtin_amdgcn_global_load_lds(
      (const __attribute__((address_space(1))) unsigned int*)g,
      (__attribute__((address_space(3))) unsigned int*)lds, 16, 0, 0);
}

// ---------------- prep_all: x->bf16 cvt + wq/wk/wv transpose ----------------
__global__ __launch_bounds__(256) void prep_all(
    const float* __restrict__ x, const float* __restrict__ wq,
    const float* __restrict__ wk, const float* __restrict__ wv,
    u16* __restrict__ xb, u16* __restrict__ wqkvt) {
  const int blk = blockIdx.x;
  if (blk < 4096) {
    int i = (blk * 256 + threadIdx.x) * 8;
    float4 a = *(const float4*)(x + i);
    float4 b = *(const float4*)(x + i + 4);
    u16 o[8];
    o[0] = f2bf(a.x); o[1] = f2bf(a.y); o[2] = f2bf(a.z); o[3] = f2bf(a.w);
    o[4] = f2bf(b.x); o[5] = f2bf(b.y); o[6] = f2bf(b.z); o[7] = f2bf(b.w);
    *(uint4*)(xb + i) = *(uint4*)&o[0];
    return;
  }
  __shared__ float t[32][33];
  const int tt = blk - 4096;
  const int k0 = (tt & 127) * 32;
  const int y = tt >> 7;
  const float* src;
  int ldn, n0;
  size_t dofs;
  if (y < 128) { src = wq; ldn = 4096; n0 = y * 32; dofs = 0; }
  else if (y < 160) { src = wk; ldn = 1024; n0 = (y - 128) * 32; dofs = (size_t)4096 * 4096; }
  else { src = wv; ldn = 1024; n0 = (y - 160) * 32; dofs = (size_t)5120 * 4096; }
  const int c = threadIdx.x & 31, r4 = threadIdx.x >> 5;
#pragma unroll
  for (int i = 0; i < 4; ++i) {
    int r = r4 + i * 8;
    t[r][c] = src[(size_t)(k0 + r) * ldn + n0 + c];
  }
  __syncthreads();
#pragma unroll
  for (int i = 0; i < 4; ++i) {
    int r = r4 + i * 8;
    wqkvt[dofs + (size_t)(n0 + r) * HID_ + k0 + c] = f2bf(t[c][r]);
  }
}

// ---------------- mid_all: wo transpose + norm_rope + v_transpose ----------
__global__ __launch_bounds__(256) void mid_all(
    const float* __restrict__ wo, const u16* __restrict__ QKV,
    const float* __restrict__ QW, const float* __restrict__ KW,
    u16* __restrict__ wot, u16* __restrict__ QB, u16* __restrict__ KB,
    u16* __restrict__ VT) {
  const int blk = blockIdx.x;
  if (blk < 16384) {  // wo transpose
    __shared__ float t[32][33];
    const int k0 = (blk & 127) * 32, n0 = (blk >> 7) * 32;
    const int c = threadIdx.x & 31, r4 = threadIdx.x >> 5;
#pragma unroll
    for (int i = 0; i < 4; ++i) {
      int r = r4 + i * 8;
      t[r][c] = wo[(size_t)(k0 + r) * HID_ + n0 + c];
    }
    __syncthreads();
#pragma unroll
    for (int i = 0; i < 4; ++i) {
      int r = r4 + i * 8;
      wot[(size_t)(n0 + r) * HID_ + k0 + c] = f2bf(t[c][r]);
    }
    return;
  }
  if (blk < 36864) {  // norm_rope
    const float QSCALE = 0.08838834764831845f * 1.4426950408889634f;
    int vec = (blk - 16384) * 4 + (threadIdx.x >> 6);
    int lane = threadIdx.x & 63;
    const u16* src;
    u16* dst;
    const float* nw;
    int m;
    float outsc;
    if (vec < 65536) {  // q
      m = vec >> 5;
      int hh = vec & 31;
      src = QKV + (size_t)m * NQKV_ + hh * 128;
      int b = m >> 10, s = m & 1023;
      dst = QB + (size_t)((b * NH_ + hh) * SEQ_ + s) * HD_;
      nw = QW;
      outsc = QSCALE;
    } else {  // k
      int vk = vec - 65536;
      m = vk >> 3;
      int kvh = vk & 7;
      src = QKV + (size_t)m * NQKV_ + 4096 + kvh * 128;
      int b = m >> 10, s = m & 1023;
      dst = KB + (size_t)((b * NKV_ + kvh) * SEQ_ + s) * HD_;
      nw = KW;
      outsc = 1.0f;
    }
    float t1 = bf2f(src[lane]), t2 = bf2f(src[lane + 64]);
    float ss = t1 * t1 + t2 * t2;
#pragma unroll
    for (int off = 32; off >= 1; off >>= 1) ss += __shfl_xor(ss, off);
    float scale = rsqrtf(ss * (1.0f / 128.0f) + 1e-6f) * outsc;
    float n1 = t1 * scale * nw[lane];
    float n2 = t2 * scale * nw[lane + 64];
    int spos = m & 1023;
    float invf = powf(10000.0f, -(float)lane * (1.0f / 64.0f));
    float ang = (float)spos * invf;
    float sn, cs;
    sincosf(ang, &sn, &cs);
    dst[lane] = f2bf(n1 * cs - n2 * sn);
    dst[lane + 64] = f2bf(n1 * sn + n2 * cs);
    return;
  }
  {  // v_transpose
    __shared__ u16 t[32][33];
    const int tt = blk - 36864;
    const int s0 = (tt & 31) * 32, d0 = ((tt >> 5) & 3) * 32;
    const int bkvh = tt >> 7;
    const int b = bkvh >> 3, kvh = bkvh & 7;
    const int c = threadIdx.x & 31, r8 = threadIdx.x >> 5;
#pragma unroll
    for (int i = 0; i < 4; ++i) {
      int r = r8 + i * 8;
      t[r][c] =
          QKV[(size_t)(b * SEQ_ + s0 + r) * NQKV_ + 5120 + kvh * 128 + d0 + c];
    }
    __syncthreads();
#pragma unroll
    for (int i = 0; i < 4; ++i) {
      int r = r8 + i * 8;
      VT[(size_t)(bkvh * HD_ + d0 + r) * SEQ_ + s0 + c] = t[c][r];
    }
  }
}

// ---------------- 256^2 8-phase GEMM: C[M x N] = A[M x K] @ Bt[N x K]^T ----
// 512 threads = 8 waves (2M x 4N); per-wave 128x64 out; BK=64, 2 dbuf slots.
// LDS layout per slot: [256 rows][64 k] bf16, phys_byte = log ^ ((row&7)<<4).
// Staging quarters (64 rows x 64 k = 1 gld16/wave) with inverse-swizzled
// global source; steady-state schedule per tile t (slot s = t&1, sn = s^1):
//   ph0(ks0,qm0): rd B+A | stage Bq0,Bq1(t+1)->sn | bar | 16 MFMA | vmcnt(4) bar
//   ph1(ks0,qm1): rd A   | stage Bq2,Bq3(t+1)->sn | bar | 16 MFMA | bar
//   ph2(ks1,qm0): rd B+A | stage Aq1,Aq3(t+1)->sn | bar | 16 MFMA | bar
//   ph3(ks1,qm1): rd A   | stage Aq0,Aq2(t+2)->s  | bar | 16 MFMA | vmcnt(4) bar
// (Aq0/Aq2 of slot s are free after ph2's 2nd barrier -> t+2 restage is safe.)

#define RD_A(QMOFS, ACOL)                                                  \
  _Pragma("unroll") for (int mfl = 0; mfl < 4; ++mfl) af[mfl] =            \
      *(const bf16x8*)&aS[(arow0 + (QMOFS) + mfl * 16) * 64 + (ACOL)];
#define RD_B(ACOL)                                                         \
  _Pragma("unroll") for (int nf = 0; nf < 4; ++nf) bf[nf] =                \
      *(const bf16x8*)&bS[(brow0 + nf * 16) * 64 + (ACOL)];
#define MM(QB)                                                             \
  _Pragma("unroll") for (int mfl = 0; mfl < 4; ++mfl)                      \
  _Pragma("unroll") for (int nf = 0; nf < 4; ++nf) acc[(QB) + mfl][nf] =   \
      mfma16(af[mfl], bf[nf], acc[(QB) + mfl][nf]);
#define BAR() __builtin_amdgcn_s_barrier()
#define PRIO1() __builtin_amdgcn_s_setprio(1)
#define PRIO0() __builtin_amdgcn_s_setprio(0)
#define SCB() __builtin_amdgcn_sched_barrier(0)

template <bool F32OUT>
__global__ __launch_bounds__(512, 2) void gemm256(
    const u16* __restrict__ A, const u16* __restrict__ Bt,
    void* __restrict__ Cv, int K, int ldc, int nbn) {
  __shared__ __align__(16) u16 As[2][16384];
  __shared__ __align__(16) u16 Bs[2][16384];

  // T1: XCD-aware swizzle (grid is a multiple of 8); chunk = one bm row.
  const int cpx = gridDim.x >> 3;
  const int sw = (blockIdx.x & 7) * cpx + (blockIdx.x >> 3);
  const int bm = sw / nbn, bn = sw % nbn;

  const int tid = threadIdx.x;
  const int w = tid >> 6, lane = tid & 63;
  const int wm = w >> 2, wn = w & 3;
  const int ln = lane & 15, quad = lane >> 4;

  // staging: lane's global source (inverse-swizzled so LDS dest is linear)
  const int srow = lane >> 3;
  const int scol = ((lane & 7) ^ srow) * 8;
  const u16 *ag0, *ag1, *ag2, *ag3, *bg0, *bg1, *bg2, *bg3;
  {
    const size_t ra = (size_t)(bm * 256 + w * 8 + srow) * K + scol;
    ag0 = A + ra;
    ag1 = A + ra + (size_t)64 * K;
    ag2 = A + ra + (size_t)128 * K;
    ag3 = A + ra + (size_t)192 * K;
    const size_t rb = (size_t)(bn * 256 + w * 8 + srow) * K + scol;
    bg0 = Bt + rb;
    bg1 = Bt + rb + (size_t)64 * K;
    bg2 = Bt + rb + (size_t)128 * K;
    bg3 = Bt + rb + (size_t)192 * K;
  }
  u16* const aw = &As[0][0] + w * 512;  // + slot_ofs + q*4096
  u16* const bw = &Bs[0][0] + w * 512;

  // fragment reads (swizzled): u16 col = (ks*32 + quad*8) ^ ((ln&7)*8)
  const int acol0 = (quad * 8) ^ ((ln & 7) << 3);
  const int acol1 = (32 + quad * 8) ^ ((ln & 7) << 3);
  const int arow0 = wm * 128 + ln;
  const int brow0 = wn * 64 + ln;

  f32x4 acc[8][4];
#pragma unroll
  for (int i = 0; i < 8; ++i)
#pragma unroll
    for (int j = 0; j < 4; ++j)
#pragma unroll
      for (int r = 0; r < 4; ++r) acc[i][j][r] = 0.0f;

  const int nt = K >> 6;  // requires nt >= 3, nt even

  // prologue: Aq0q2(0), Bq0q1(0), Bq2q3(0), Aq1q3(0), Aq0q2(1)  (10 gld/wave)
  gld16(aw + 0, ag0);
  gld16(aw + 8192, ag2);
  gld16(bw + 0, bg0);
  gld16(bw + 4096, bg1);
  gld16(bw + 8192, bg2);
  gld16(bw + 12288, bg3);
  gld16(aw + 4096, ag1);
  gld16(aw + 12288, ag3);
  gld16(aw + 16384 + 0, ag0 + 64);
  gld16(aw + 16384 + 8192, ag2 + 64);
  ag0 += 128; ag2 += 128; ag1 += 64; ag3 += 64;
  bg0 += 64; bg1 += 64; bg2 += 64; bg3 += 64;
  asm volatile("s_waitcnt vmcnt(4)" ::: "memory");
  BAR();
  SCB();

  int sofs = 0;
#pragma unroll 1
  for (int t = 0; t < nt - 2; ++t) {
    const int so = sofs, sn = sofs ^ 16384;
    const u16* aS = &As[0][0] + so;
    const u16* bS = &Bs[0][0] + so;
    bf16x8 af[4], bf[4];
    // ---- ph0 (ks0, qm0)
    RD_B(acol0);
    RD_A(0, acol0);
    gld16(bw + sn + 0, bg0);
    gld16(bw + sn + 4096, bg1);
    BAR();
    PRIO1();
    MM(0);
    PRIO0();
    asm volatile("s_waitcnt vmcnt(4)" ::: "memory");
    BAR();
    SCB();
    // ---- ph1 (ks0, qm1)  B frags reused from regs
    RD_A(64, acol0);
    gld16(bw + sn + 8192, bg2);
    gld16(bw + sn + 12288, bg3);
    BAR();
    PRIO1();
    MM(4);
    PRIO0();
    BAR();
    // ---- ph2 (ks1, qm0)
    RD_B(acol1);
    RD_A(0, acol1);
    gld16(aw + sn + 4096, ag1);
    gld16(aw + sn + 12288, ag3);
    BAR();
    PRIO1();
    MM(0);
    PRIO0();
    BAR();
    // ---- ph3 (ks1, qm1)  restage Aq0/Aq2 of CURRENT slot for tile t+2
    RD_A(64, acol1);
    gld16(aw + so + 0, ag0);
    gld16(aw + so + 8192, ag2);
    BAR();
    PRIO1();
    MM(4);
    PRIO0();
    asm volatile("s_waitcnt vmcnt(4)" ::: "memory");
    BAR();
    SCB();
    ag0 += 64; ag1 += 64; ag2 += 64; ag3 += 64;
    bg0 += 64; bg1 += 64; bg2 += 64; bg3 += 64;
    sofs ^= 16384;
  }
  {  // tile nt-2: no ph3 staging; drain to 2
    const int so = sofs, sn = sofs ^ 16384;
    const u16* aS = &As[0][0] + so;
    const u16* bS = &Bs[0][0] + so;
    bf16x8 af[4], bf[4];
    RD_B(acol0);
    RD_A(0, acol0);
    gld16(bw + sn + 0, bg0);
    gld16(bw + sn + 4096, bg1);
    BAR();
    PRIO1();
    MM(0);
    PRIO0();
    asm volatile("s_waitcnt vmcnt(4)" ::: "memory");
    BAR();
    SCB();
    RD_A(64, acol0);
    gld16(bw + sn + 8192, bg2);
    gld16(bw + sn + 12288, bg3);
    BAR();
    PRIO1();
    MM(4);
    PRIO0();
    BAR();
    RD_B(acol1);
    RD_A(0, acol1);
    gld16(aw + sn + 4096, ag1);
    gld16(aw + sn + 12288, ag3);
    BAR();
    PRIO1();
    MM(0);
    PRIO0();
    BAR();
    RD_A(64, acol1);
    BAR();
    PRIO1();
    MM(4);
    PRIO0();
    asm volatile("s_waitcnt vmcnt(2)" ::: "memory");
    BAR();
    SCB();
    sofs ^= 16384;
  }
  {  // tile nt-1: no staging; drain to 0 after ph0
    const int so = sofs;
    const u16* aS = &As[0][0] + so;
    const u16* bS = &Bs[0][0] + so;
    bf16x8 af[4], bf[4];
    RD_B(acol0);
    RD_A(0, acol0);
    BAR();
    PRIO1();
    MM(0);
    PRIO0();
    asm volatile("s_waitcnt vmcnt(0)" ::: "memory");
    BAR();
    SCB();
    RD_A(64, acol0);
    BAR();
    PRIO1();
    MM(4);
    PRIO0();
    BAR();
    RD_B(acol1);
    RD_A(0, acol1);
    BAR();
    PRIO1();
    MM(0);
    PRIO0();
    BAR();
    RD_A(64, acol1);
    PRIO1();
    MM(4);
    PRIO0();
  }

  // epilogue: C write
  const int gcol = bn * 256 + wn * 64 + ln;
#pragma unroll
  for (int mfg = 0; mfg < 8; ++mfg) {
#pragma unroll
    for (int r = 0; r < 4; ++r) {
      const int grow = bm * 256 + wm * 128 + mfg * 16 + quad * 4 + r;
      if (F32OUT) {
        float* dst = (float*)Cv + (size_t)grow * ldc + gcol;
#pragma unroll
        for (int nf = 0; nf < 4; ++nf) dst[nf * 16] = acc[mfg][nf][r];
      } else {
        u16* dst = (u16*)Cv + (size_t)grow * ldc + gcol;
#pragma unroll
        for (int nf = 0; nf < 4; ++nf) dst[nf * 16] = f2bf(acc[mfg][nf][r]);
      }
    }
  }
}

#undef RD_A
#undef RD_B
#undef MM
#undef BAR
#undef PRIO1
#undef PRIO0
#undef SCB

// ---------------- GQA causal flash attention (R3 version) ----------------
__global__ __launch_bounds__(256) void flash_attn(
    const u16* __restrict__ QB, const u16* __restrict__ KB,
    const u16* __restrict__ VT, u16* __restrict__ CTX) {
  __shared__ u16 Ks[4][64][32];   // [kc][key][k-seg]   16 KB
  __shared__ u16 Vs[2][128][32];  // [kchunk][d][key]   16 KB
  __shared__ u16 Pl[4][16][72];   // per-wave P, A-layout, XOR-bit3 swizzle

  const int bid = blockIdx.x;
  const int qt = 15 - (bid >> 6);  // long blocks dispatch first
  const int h = bid & 31, b = (bid >> 5) & 1;
  const int kvh = h >> 2;
  const int tid = threadIdx.x, w = tid >> 6, lane = tid & 63;
  const int ln = lane & 15, quad = lane >> 4;
  const int l4 = lane >> 2, l4r = lane & 3;

  const u16* qbase =
      QB + (size_t)((b * NH_ + h) * SEQ_ + qt * 64 + w * 16 + ln) * HD_;
  bf16x8 qf[4];
#pragma unroll
  for (int kc = 0; kc < 4; ++kc)
    qf[kc] = *(const bf16x8*)(qbase + kc * 32 + quad * 8);

  f32x4 o[8];
#pragma unroll
  for (int t = 0; t < 8; ++t)
#pragma unroll
    for (int r = 0; r < 4; ++r) o[t][r] = 0.0f;
  float m_r[4] = {-3e38f, -3e38f, -3e38f, -3e38f};
  float l_r[4] = {0.0f, 0.0f, 0.0f, 0.0f};

  const u16* krow =
      KB + (size_t)((b * NKV_ + kvh) * SEQ_ + w * 16 + l4) * HD_ + l4r * 8;
  const u16* vrow =
      VT + (size_t)((b * NKV_ + kvh) * HD_ + w * 32 + l4) * SEQ_ + l4r * 8;
  const int pswz = ((ln >> 3) & 1) << 3;

  for (int kt = 0; kt <= qt; ++kt) {
    const int key0 = kt * 64;
#pragma unroll
    for (int i = 0; i < 4; ++i)
      gld16(&Ks[i][w * 16][0], krow + (size_t)key0 * HD_ + i * 32);
#pragma unroll
    for (int i = 0; i < 4; ++i)
      gld16(&Vs[i & 1][w * 32 + (i >> 1) * 16][0],
            vrow + (size_t)(i >> 1) * 16 * SEQ_ + key0 + (i & 1) * 32);
    __syncthreads();

    f32x4 sc[4];
#pragma unroll
    for (int t2 = 0; t2 < 4; ++t2) {
#pragma unroll
      for (int r = 0; r < 4; ++r) sc[t2][r] = 0.0f;
#pragma unroll
      for (int kc = 0; kc < 4; ++kc) {
        bf16x8 kf = *(const bf16x8*)&Ks[kc][t2 * 16 + ln][quad * 8];
        sc[t2] = mfma16(qf[kc], kf, sc[t2]);
      }
    }

    const bool diag = (kt == qt);
    float p[4][4], alpha[4];
#pragma unroll
    for (int r = 0; r < 4; ++r) {
      float s0 = sc[0][r], s1 = sc[1][r], s2 = sc[2][r], s3 = sc[3][r];
      if (diag) {
        const int qi = qt * 64 + w * 16 + quad * 4 + r;
        if (key0 + ln > qi) s0 = -3e38f;
        if (key0 + 16 + ln > qi) s1 = -3e38f;
        if (key0 + 32 + ln > qi) s2 = -3e38f;
        if (key0 + 48 + ln > qi) s3 = -3e38f;
      }
      float mx = fmaxf(fmaxf(s0, s1), fmaxf(s2, s3));
#pragma unroll
      for (int off = 1; off < 16; off <<= 1) mx = fmaxf(mx, __shfl_xor(mx, off));
      float mnew = fmaxf(m_r[r], mx);
      alpha[r] = exp2f(m_r[r] - mnew);
      p[0][r] = exp2f(s0 - mnew);
      p[1][r] = exp2f(s1 - mnew);
      p[2][r] = exp2f(s2 - mnew);
      p[3][r] = exp2f(s3 - mnew);
      float rs = p[0][r] + p[1][r] + p[2][r] + p[3][r];
#pragma unroll
      for (int off = 1; off < 16; off <<= 1) rs += __shfl_xor(rs, off);
      l_r[r] = l_r[r] * alpha[r] + rs;
      m_r[r] = mnew;
    }
#pragma unroll
    for (int t = 0; t < 8; ++t)
#pragma unroll
      for (int r = 0; r < 4; ++r) o[t][r] *= alpha[r];

#pragma unroll
    for (int r = 0; r < 4; ++r) {
      const int row = quad * 4 + r;
      const int wswz = ((row >> 3) & 1) << 3;
#pragma unroll
      for (int t2 = 0; t2 < 4; ++t2)
        Pl[w][row][(t2 * 16 + ln) ^ wswz] = f2bf(p[t2][r]);
    }
    bf16x8 af0 = *(const bf16x8*)&Pl[w][ln][(quad * 8) ^ pswz];
    bf16x8 af1 = *(const bf16x8*)&Pl[w][ln][32 + ((quad * 8) ^ pswz)];
#pragma unroll
    for (int t = 0; t < 8; ++t) {
      bf16x8 vf0 = *(const bf16x8*)&Vs[0][t * 16 + ln][quad * 8];
      o[t] = mfma16(af0, vf0, o[t]);
      bf16x8 vf1 = *(const bf16x8*)&Vs[1][t * 16 + ln][quad * 8];
      o[t] = mfma16(af1, vf1, o[t]);
    }
    __syncthreads();
  }

#pragma unroll
  for (int r = 0; r < 4; ++r) {
    float inv_l = 1.0f / l_r[r];
    int srow = qt * 64 + w * 16 + quad * 4 + r;
    u16* dst = CTX + (size_t)(b * SEQ_ + srow) * (NH_ * HD_) + h * HD_;
#pragma unroll
    for (int t = 0; t < 8; ++t) dst[t * 16 + ln] = f2bf(o[t][r] * inv_l);
  }
}

extern "C" void kernel_launch(void* const* d_in, const int* in_sizes, int n_in,
                              void* d_out, int out_size, void* d_ws,
                              size_t ws_size, hipStream_t stream) {
  const float* x = (const float*)d_in[0];
  const float* wq = (const float*)d_in[1];
  const float* wk = (const float*)d_in[2];
  const float* wv = (const float*)d_in[3];
  const float* wo = (const float*)d_in[4];
  const float* qw = (const float*)d_in[5];
  const float* kw = (const float*)d_in[6];
  float* out = (float*)d_out;
  char* ws = (char*)d_ws;
  const size_t MB = 1024 * 1024;

  //  [0,48M):  WQKVT bf16 [6144][4096]  -> after qkv_gemm: WOT bf16 at [0,32M)
  //  [48,64M): Xb bf16 [2048][4096]     (dead after qkv_gemm)
  //  [64,88M): qkv bf16 [2048][6144]    -> ctx at [64,80M) after mid_all
  //  [88,104M): qb  [104,108M): kb  [108,112M): VT [16][128][1024]
  u16* wqkvt = (u16*)ws;
  u16* wot = (u16*)ws;
  u16* xb = (u16*)(ws + 48 * MB);
  u16* qkv = (u16*)(ws + 64 * MB);
  u16* ctx = (u16*)(ws + 64 * MB);
  u16* qb = (u16*)(ws + 88 * MB);
  u16* kb = (u16*)(ws + 104 * MB);
  u16* vt = (u16*)(ws + 108 * MB);

  prep_all<<<dim3(28672), 256, 0, stream>>>(x, wq, wk, wv, xb, wqkvt);
  gemm256<false><<<dim3(192), 512, 0, stream>>>(xb, wqkvt, qkv, 4096, 6144, 24);
  mid_all<<<dim3(38912), 256, 0, stream>>>(wo, qkv, qw, kw, wot, qb, kb, vt);
  flash_attn<<<dim3(1024), 256, 0, stream>>>(qb, kb, vt, ctx);
  gemm256<true><<<dim3(128), 512, 0, stream>>>(ctx, wot, out, 4096, 4096, 16);
}

// Round 2
// 462.391 us; speedup vs baseline: 1.1992x; 1.1992x over previous
//
#include <hip/hip_runtime.h>

// FlashQwenAttention: x@wq/wk/wv -> rmsnorm(q,k) -> rope -> GQA causal attn -> ctx@wo
// B=2 S=1024 H=4096 NH=32 NKV=8 HD=128. Inputs fp32; internal bf16 MFMA.
// R7: BM=128 8-phase GEMM, per-GEMM BN for full 256-block grids (QKV BN=384,
// proj BN=256); wave-interleaved N-frags => phase p reads exactly B-lines
// {2p,2p+1}; line-granular staging 4-6 phases ahead; steady vmcnt(11)/(8)
// (QKV) and vmcnt(6) (proj); m201-faithful phase: bar;lgkm0;prio1;16 MFMA;
// prio0;vmcnt;bar. No sched_barriers (m141).

#define NH_ 32
#define NKV_ 8
#define HD_ 128
#define SEQ_ 1024
#define HID_ 4096
#define NQKV_ 6144

typedef unsigned short u16;
typedef __bf16 bf16x8 __attribute__((ext_vector_type(8)));
typedef float f32x4 __attribute__((ext_vector_type(4)));

__device__ __forceinline__ u16 f2bf(float f) {
  unsigned int u = __float_as_uint(f);
  return (u16)((u + 0x7FFFu + ((u >> 16) & 1u)) >> 16);
}
__device__ __forceinline__ float bf2f(u16 u) {
  return __uint_as_float(((unsigned int)u) << 16);
}
__device__ __forceinline__ f32x4 mfma16(bf16x8 a, bf16x8 b, f32x4 c) {
  return __builtin_amdgcn_mfma_f32_16x16x32_bf16(a, b, c, 0, 0, 0);
}
__device__ __forceinline__ void gld16(u16* lds, const u16* g) {
  __builtin_amdgcn_global_load_lds(
      (const __attribute__((address_space(1))) unsigned int*)g,
      (__attribute__((address_space(3))) unsigned int*)lds, 16, 0, 0);
}

// ---------------- prep_all: x->bf16 cvt + wq/wk/wv transpose ----------------
__global__ __launch_bounds__(256) void prep_all(
    const float* __restrict__ x, const float* __restrict__ wq,
    const float* __restrict__ wk, const float* __restrict__ wv,
    u16* __restrict__ xb, u16* __restrict__ wqkvt) {
  const int blk = blockIdx.x;
  if (blk < 4096) {
    int i = (blk * 256 + threadIdx.x) * 8;
    float4 a = *(const float4*)(x + i);
    float4 b = *(const float4*)(x + i + 4);
    u16 o[8];
    o[0] = f2bf(a.x); o[1] = f2bf(a.y); o[2] = f2bf(a.z); o[3] = f2bf(a.w);
    o[4] = f2bf(b.x); o[5] = f2bf(b.y); o[6] = f2bf(b.z); o[7] = f2bf(b.w);
    *(uint4*)(xb + i) = *(uint4*)&o[0];
    return;
  }
  __shared__ float t[32][33];
  const int tt = blk - 4096;
  const int k0 = (tt & 127) * 32;
  const int y = tt >> 7;
  const float* src;
  int ldn, n0;
  size_t dofs;
  if (y < 128) { src = wq; ldn = 4096; n0 = y * 32; dofs = 0; }
  else if (y < 160) { src = wk; ldn = 1024; n0 = (y - 128) * 32; dofs = (size_t)4096 * 4096; }
  else { src = wv; ldn = 1024; n0 = (y - 160) * 32; dofs = (size_t)5120 * 4096; }
  const int c = threadIdx.x & 31, r4 = threadIdx.x >> 5;
#pragma unroll
  for (int i = 0; i < 4; ++i) {
    int r = r4 + i * 8;
    t[r][c] = src[(size_t)(k0 + r) * ldn + n0 + c];
  }
  __syncthreads();
#pragma unroll
  for (int i = 0; i < 4; ++i) {
    int r = r4 + i * 8;
    wqkvt[dofs + (size_t)(n0 + r) * HID_ + k0 + c] = f2bf(t[c][r]);
  }
}

// ---------------- mid_all: wo transpose + norm_rope + v_transpose ----------
__global__ __launch_bounds__(256) void mid_all(
    const float* __restrict__ wo, const u16* __restrict__ QKV,
    const float* __restrict__ QW, const float* __restrict__ KW,
    u16* __restrict__ wot, u16* __restrict__ QB, u16* __restrict__ KB,
    u16* __restrict__ VT) {
  const int blk = blockIdx.x;
  if (blk < 16384) {  // wo transpose
    __shared__ float t[32][33];
    const int k0 = (blk & 127) * 32, n0 = (blk >> 7) * 32;
    const int c = threadIdx.x & 31, r4 = threadIdx.x >> 5;
#pragma unroll
    for (int i = 0; i < 4; ++i) {
      int r = r4 + i * 8;
      t[r][c] = wo[(size_t)(k0 + r) * HID_ + n0 + c];
    }
    __syncthreads();
#pragma unroll
    for (int i = 0; i < 4; ++i) {
      int r = r4 + i * 8;
      wot[(size_t)(n0 + r) * HID_ + k0 + c] = f2bf(t[c][r]);
    }
    return;
  }
  if (blk < 36864) {  // norm_rope
    const float QSCALE = 0.08838834764831845f * 1.4426950408889634f;
    int vec = (blk - 16384) * 4 + (threadIdx.x >> 6);
    int lane = threadIdx.x & 63;
    const u16* src;
    u16* dst;
    const float* nw;
    int m;
    float outsc;
    if (vec < 65536) {  // q
      m = vec >> 5;
      int hh = vec & 31;
      src = QKV + (size_t)m * NQKV_ + hh * 128;
      int b = m >> 10, s = m & 1023;
      dst = QB + (size_t)((b * NH_ + hh) * SEQ_ + s) * HD_;
      nw = QW;
      outsc = QSCALE;
    } else {  // k
      int vk = vec - 65536;
      m = vk >> 3;
      int kvh = vk & 7;
      src = QKV + (size_t)m * NQKV_ + 4096 + kvh * 128;
      int b = m >> 10, s = m & 1023;
      dst = KB + (size_t)((b * NKV_ + kvh) * SEQ_ + s) * HD_;
      nw = KW;
      outsc = 1.0f;
    }
    float t1 = bf2f(src[lane]), t2 = bf2f(src[lane + 64]);
    float ss = t1 * t1 + t2 * t2;
#pragma unroll
    for (int off = 32; off >= 1; off >>= 1) ss += __shfl_xor(ss, off);
    float scale = rsqrtf(ss * (1.0f / 128.0f) + 1e-6f) * outsc;
    float n1 = t1 * scale * nw[lane];
    float n2 = t2 * scale * nw[lane + 64];
    int spos = m & 1023;
    float invf = powf(10000.0f, -(float)lane * (1.0f / 64.0f));
    float ang = (float)spos * invf;
    float sn, cs;
    sincosf(ang, &sn, &cs);
    dst[lane] = f2bf(n1 * cs - n2 * sn);
    dst[lane + 64] = f2bf(n1 * sn + n2 * cs);
    return;
  }
  {  // v_transpose
    __shared__ u16 t[32][33];
    const int tt = blk - 36864;
    const int s0 = (tt & 31) * 32, d0 = ((tt >> 5) & 3) * 32;
    const int bkvh = tt >> 7;
    const int b = bkvh >> 3, kvh = bkvh & 7;
    const int c = threadIdx.x & 31, r8 = threadIdx.x >> 5;
#pragma unroll
    for (int i = 0; i < 4; ++i) {
      int r = r8 + i * 8;
      t[r][c] =
          QKV[(size_t)(b * SEQ_ + s0 + r) * NQKV_ + 5120 + kvh * 128 + d0 + c];
    }
    __syncthreads();
#pragma unroll
    for (int i = 0; i < 4; ++i) {
      int r = r8 + i * 8;
      VT[(size_t)(bkvh * HD_ + d0 + r) * SEQ_ + s0 + c] = t[c][r];
    }
  }
}

// ------- 8-phase GEMM, BM=128, BN=NF*64: C[M x N] = A[M x K] @ Bt[N x K]^T --
// 512 thr = 8 waves (2M x 4N). Per-wave out 64 x (NF*16), N-frags interleaved:
// global n-frag g owned by wave g&3, frag index f=g>>2. Phase p (of NP=NF/2
// per K-tile) computes n-frag pair {2p,2p+1} x K=64 = 16 MFMA, reading
// B LDS lines {2p,2p+1} (line = 64 N-rows x 64 k). A (2 lines) read at ph0,
// held in regs. LDS swizzle: u16 idx = row*64 + (col ^ ((row&7)<<3)); staged
// via inverse-swizzled global source + linear gld16 dest.
// Staging rhythm (tile t, slot s=t&1): ph0: t+1's B lines {NF-2,NF-1}->s^1;
// ph1: t+2's {A0,A1,B0(,B1 if NP=2)}->s (regions died at ph0 bar2);
// ph2 (NP=3): t+2's {B1,B2,B3}->s. Steady waits: NP=3: ph1 vmcnt(11),
// ph2 vmcnt(8); NP=2: vmcnt(6) each phase. Epilogue drains ...->2->0.

#define BAR() __builtin_amdgcn_s_barrier()
#define PRIO1() __builtin_amdgcn_s_setprio(1)
#define PRIO0() __builtin_amdgcn_s_setprio(0)
#define LGKM0() asm volatile("s_waitcnt lgkmcnt(0)" ::: "memory")
#define LGKM8() asm volatile("s_waitcnt lgkmcnt(8)" ::: "memory")
#define VM(n) asm volatile("s_waitcnt vmcnt(" #n ")" ::: "memory")

#define STGA(slot, l, koff) \
  gld16(&L[(slot)*SLOT + (l)*4096 + wofs], aB + (size_t)(l)*64*K + (koff))
#define STGB(slot, l, koff) \
  gld16(&L[(slot)*SLOT + 8192 + (l)*4096 + wofs], bB + (size_t)(l)*64*K + (koff))

#define PH_READS(p)                                                       \
  if ((p) == 0) {                                                         \
    _Pragma("unroll") for (int m = 0; m < 4; ++m)                         \
        af[0][m] = *(const bf16x8*)&Ls[aro + m * 1024 + acS0];            \
    _Pragma("unroll") for (int m = 0; m < 4; ++m)                         \
        af[1][m] = *(const bf16x8*)&Ls[aro + m * 1024 + acS1];            \
  }                                                                       \
  bf[0][0] = *(const bf16x8*)&Ls[bro + (p)*8192 + acS0];                  \
  bf[0][1] = *(const bf16x8*)&Ls[bro + (p)*8192 + 4096 + acS0];           \
  bf[1][0] = *(const bf16x8*)&Ls[bro + (p)*8192 + acS1];                  \
  bf[1][1] = *(const bf16x8*)&Ls[bro + (p)*8192 + 4096 + acS1];

#define PH_MM(p)                                                          \
  _Pragma("unroll") for (int kk = 0; kk < 2; ++kk)                        \
  _Pragma("unroll") for (int m = 0; m < 4; ++m)                           \
  _Pragma("unroll") for (int j = 0; j < 2; ++j)                           \
      acc[m][2 * (p) + j] = mfma16(af[kk][m], bf[kk][j], acc[m][2 * (p) + j]);

template <int NF, bool F32OUT>
__global__ __launch_bounds__(512, 2) void gemm8p(
    const u16* __restrict__ A, const u16* __restrict__ Bt,
    void* __restrict__ Cv, const int K, const int ldc) {
  constexpr int BN = NF * 64;
  constexpr int NP = NF / 2;
  constexpr int SLOT = (128 + BN) * 64;  // u16 per dbuf slot
  __shared__ __align__(16) u16 L[2 * SLOT];

  // T1: XCD swizzle; grid 256 = 16bm x 16bn, 32 blocks (2 bm rows) per XCD.
  const int sw = (blockIdx.x & 7) * 32 + (blockIdx.x >> 3);
  const int bm = sw >> 4, bn = sw & 15;

  const int tid = threadIdx.x, w = tid >> 6, lane = tid & 63;
  const int wm = w >> 2, wn = w & 3;
  const int ln = lane & 15, quad = lane >> 4;

  // staging source (inverse-swizzled so gld16's linear LDS dest lands right)
  const int srow = lane >> 3;
  const int scol = ((lane & 7) ^ srow) * 8;
  const u16* aB = A + (size_t)(bm * 128 + w * 8 + srow) * K + scol;
  const u16* bB = Bt + (size_t)(bn * BN + w * 8 + srow) * K + scol;
  const int wofs = w * 512;

  // swizzled fragment read columns (row&7 == ln&7 for all frag rows)
  const int acS0 = (quad * 8) ^ ((ln & 7) << 3);
  const int acS1 = (32 + quad * 8) ^ ((ln & 7) << 3);
  const int aro = (wm * 64 + ln) * 64;
  const int bro = 8192 + (wn * 16 + ln) * 64;

  f32x4 acc[4][NF];
#pragma unroll
  for (int m = 0; m < 4; ++m)
#pragma unroll
    for (int f = 0; f < NF; ++f)
#pragma unroll
      for (int r = 0; r < 4; ++r) acc[m][f][r] = 0.0f;

  const int nt = K >> 6;  // K-tiles (>=3)

  // ---- prologue: tile0 fully, tile1 head lines; leave t1 lines in flight
  STGA(0, 0, 0);
  STGA(0, 1, 0);
#pragma unroll
  for (int l = 0; l < NF; ++l) STGB(0, l, 0);
  STGA(1, 0, 64);
  STGA(1, 1, 64);
  STGB(1, 0, 64);
  if constexpr (NP == 3) {
    STGB(1, 1, 64); STGB(1, 2, 64); STGB(1, 3, 64);
    VM(6);
  } else {
    STGB(1, 1, 64);
    VM(4);
  }
  BAR();

  bf16x8 af[2][4], bf[2][2];
  int s = 0;
#pragma unroll 2
  for (int t = 0; t < nt - 2; ++t) {
    const u16* Ls = &L[s * SLOT];
    const int sn = s ^ 1;
    const int k1 = (t + 1) << 6, k2 = (t + 2) << 6;
    // ---- ph0
    PH_READS(0);
    STGB(sn, NF - 2, k1);
    STGB(sn, NF - 1, k1);
    LGKM8();
    BAR();
    LGKM0();
    PRIO1(); PH_MM(0); PRIO0();
    if constexpr (NP == 2) VM(6);
    BAR();
    // ---- ph1
    PH_READS(1);
    STGA(s, 0, k2);
    STGA(s, 1, k2);
    STGB(s, 0, k2);
    if constexpr (NP == 2) STGB(s, 1, k2);
    BAR();
    LGKM0();
    PRIO1(); PH_MM(1); PRIO0();
    if constexpr (NP == 3) { VM(11); } else { VM(6); }
    BAR();
    if constexpr (NP == 3) {
      // ---- ph2
      PH_READS(2);
      STGB(s, 1, k2);
      STGB(s, 2, k2);
      STGB(s, 3, k2);
      BAR();
      LGKM0();
      PRIO1(); PH_MM(2); PRIO0();
      VM(8);
      BAR();
    }
    s = sn;
  }
  {  // ---- tile nt-2: stage only t+1's tail B lines; drain toward 2
    const u16* Ls = &L[s * SLOT];
    const int sn = s ^ 1;
    const int k1 = (nt - 1) << 6;
    PH_READS(0);
    STGB(sn, NF - 2, k1);
    STGB(sn, NF - 1, k1);
    LGKM8();
    BAR();
    LGKM0();
    PRIO1(); PH_MM(0); PRIO0();
    if constexpr (NP == 2) VM(6);
    BAR();
    PH_READS(1);
    BAR();
    LGKM0();
    PRIO1(); PH_MM(1); PRIO0();
    if constexpr (NP == 3) { VM(8); } else { VM(2); }
    BAR();
    if constexpr (NP == 3) {
      PH_READS(2);
      BAR();
      LGKM0();
      PRIO1(); PH_MM(2); PRIO0();
      VM(2);
      BAR();
    }
    s = sn;
  }
  {  // ---- tile nt-1: no staging; drain to 0
    const u16* Ls = &L[s * SLOT];
    PH_READS(0);
    BAR();
    LGKM0();
    PRIO1(); PH_MM(0); PRIO0();
    if constexpr (NP == 2) VM(0);
    BAR();
    PH_READS(1);
    BAR();
    LGKM0();
    PRIO1(); PH_MM(1); PRIO0();
    if constexpr (NP == 3) {
      VM(0);
      BAR();
      PH_READS(2);
      BAR();
      LGKM0();
      PRIO1(); PH_MM(2); PRIO0();
    }
  }

  // ---- epilogue: C write (wave wn owns n-frags g = f*4+wn)
  const int colb = bn * BN + wn * 16 + ln;
#pragma unroll
  for (int m = 0; m < 4; ++m) {
#pragma unroll
    for (int r = 0; r < 4; ++r) {
      const int grow = bm * 128 + wm * 64 + m * 16 + quad * 4 + r;
      if (F32OUT) {
        float* dst = (float*)Cv + (size_t)grow * ldc + colb;
#pragma unroll
        for (int f = 0; f < NF; ++f) dst[f * 64] = acc[m][f][r];
      } else {
        u16* dst = (u16*)Cv + (size_t)grow * ldc + colb;
#pragma unroll
        for (int f = 0; f < NF; ++f) dst[f * 64] = f2bf(acc[m][f][r]);
      }
    }
  }
}

#undef PH_READS
#undef PH_MM
#undef STGA
#undef STGB
#undef BAR
#undef PRIO1
#undef PRIO0
#undef LGKM0
#undef LGKM8
#undef VM

// ---------------- GQA causal flash attention (R3 version) ----------------
__global__ __launch_bounds__(256) void flash_attn(
    const u16* __restrict__ QB, const u16* __restrict__ KB,
    const u16* __restrict__ VT, u16* __restrict__ CTX) {
  __shared__ u16 Ks[4][64][32];   // [kc][key][k-seg]   16 KB
  __shared__ u16 Vs[2][128][32];  // [kchunk][d][key]   16 KB
  __shared__ u16 Pl[4][16][72];   // per-wave P, A-layout, XOR-bit3 swizzle

  const int bid = blockIdx.x;
  const int qt = 15 - (bid >> 6);  // long blocks dispatch first
  const int h = bid & 31, b = (bid >> 5) & 1;
  const int kvh = h >> 2;
  const int tid = threadIdx.x, w = tid >> 6, lane = tid & 63;
  const int ln = lane & 15, quad = lane >> 4;
  const int l4 = lane >> 2, l4r = lane & 3;

  const u16* qbase =
      QB + (size_t)((b * NH_ + h) * SEQ_ + qt * 64 + w * 16 + ln) * HD_;
  bf16x8 qf[4];
#pragma unroll
  for (int kc = 0; kc < 4; ++kc)
    qf[kc] = *(const bf16x8*)(qbase + kc * 32 + quad * 8);

  f32x4 o[8];
#pragma unroll
  for (int t = 0; t < 8; ++t)
#pragma unroll
    for (int r = 0; r < 4; ++r) o[t][r] = 0.0f;
  float m_r[4] = {-3e38f, -3e38f, -3e38f, -3e38f};
  float l_r[4] = {0.0f, 0.0f, 0.0f, 0.0f};

  const u16* krow =
      KB + (size_t)((b * NKV_ + kvh) * SEQ_ + w * 16 + l4) * HD_ + l4r * 8;
  const u16* vrow =
      VT + (size_t)((b * NKV_ + kvh) * HD_ + w * 32 + l4) * SEQ_ + l4r * 8;
  const int pswz = ((ln >> 3) & 1) << 3;

  for (int kt = 0; kt <= qt; ++kt) {
    const int key0 = kt * 64;
#pragma unroll
    for (int i = 0; i < 4; ++i)
      gld16(&Ks[i][w * 16][0], krow + (size_t)key0 * HD_ + i * 32);
#pragma unroll
    for (int i = 0; i < 4; ++i)
      gld16(&Vs[i & 1][w * 32 + (i >> 1) * 16][0],
            vrow + (size_t)(i >> 1) * 16 * SEQ_ + key0 + (i & 1) * 32);
    __syncthreads();

    f32x4 sc[4];
#pragma unroll
    for (int t2 = 0; t2 < 4; ++t2) {
#pragma unroll
      for (int r = 0; r < 4; ++r) sc[t2][r] = 0.0f;
#pragma unroll
      for (int kc = 0; kc < 4; ++kc) {
        bf16x8 kf = *(const bf16x8*)&Ks[kc][t2 * 16 + ln][quad * 8];
        sc[t2] = mfma16(qf[kc], kf, sc[t2]);
      }
    }

    const bool diag = (kt == qt);
    float p[4][4], alpha[4];
#pragma unroll
    for (int r = 0; r < 4; ++r) {
      float s0 = sc[0][r], s1 = sc[1][r], s2 = sc[2][r], s3 = sc[3][r];
      if (diag) {
        const int qi = qt * 64 + w * 16 + quad * 4 + r;
        if (key0 + ln > qi) s0 = -3e38f;
        if (key0 + 16 + ln > qi) s1 = -3e38f;
        if (key0 + 32 + ln > qi) s2 = -3e38f;
        if (key0 + 48 + ln > qi) s3 = -3e38f;
      }
      float mx = fmaxf(fmaxf(s0, s1), fmaxf(s2, s3));
#pragma unroll
      for (int off = 1; off < 16; off <<= 1) mx = fmaxf(mx, __shfl_xor(mx, off));
      float mnew = fmaxf(m_r[r], mx);
      alpha[r] = exp2f(m_r[r] - mnew);
      p[0][r] = exp2f(s0 - mnew);
      p[1][r] = exp2f(s1 - mnew);
      p[2][r] = exp2f(s2 - mnew);
      p[3][r] = exp2f(s3 - mnew);
      float rs = p[0][r] + p[1][r] + p[2][r] + p[3][r];
#pragma unroll
      for (int off = 1; off < 16; off <<= 1) rs += __shfl_xor(rs, off);
      l_r[r] = l_r[r] * alpha[r] + rs;
      m_r[r] = mnew;
    }
#pragma unroll
    for (int t = 0; t < 8; ++t)
#pragma unroll
      for (int r = 0; r < 4; ++r) o[t][r] *= alpha[r];

#pragma unroll
    for (int r = 0; r < 4; ++r) {
      const int row = quad * 4 + r;
      const int wswz = ((row >> 3) & 1) << 3;
#pragma unroll
      for (int t2 = 0; t2 < 4; ++t2)
        Pl[w][row][(t2 * 16 + ln) ^ wswz] = f2bf(p[t2][r]);
    }
    bf16x8 af0 = *(const bf16x8*)&Pl[w][ln][(quad * 8) ^ pswz];
    bf16x8 af1 = *(const bf16x8*)&Pl[w][ln][32 + ((quad * 8) ^ pswz)];
#pragma unroll
    for (int t = 0; t < 8; ++t) {
      bf16x8 vf0 = *(const bf16x8*)&Vs[0][t * 16 + ln][quad * 8];
      o[t] = mfma16(af0, vf0, o[t]);
      bf16x8 vf1 = *(const bf16x8*)&Vs[1][t * 16 + ln][quad * 8];
      o[t] = mfma16(af1, vf1, o[t]);
    }
    __syncthreads();
  }

#pragma unroll
  for (int r = 0; r < 4; ++r) {
    float inv_l = 1.0f / l_r[r];
    int srow = qt * 64 + w * 16 + quad * 4 + r;
    u16* dst = CTX + (size_t)(b * SEQ_ + srow) * (NH_ * HD_) + h * HD_;
#pragma unroll
    for (int t = 0; t < 8; ++t) dst[t * 16 + ln] = f2bf(o[t][r] * inv_l);
  }
}

extern "C" void kernel_launch(void* const* d_in, const int* in_sizes, int n_in,
                              void* d_out, int out_size, void* d_ws,
                              size_t ws_size, hipStream_t stream) {
  const float* x = (const float*)d_in[0];
  const float* wq = (const float*)d_in[1];
  const float* wk = (const float*)d_in[2];
  const float* wv = (const float*)d_in[3];
  const float* wo = (const float*)d_in[4];
  const float* qw = (const float*)d_in[5];
  const float* kw = (const float*)d_in[6];
  float* out = (float*)d_out;
  char* ws = (char*)d_ws;
  const size_t MB = 1024 * 1024;

  //  [0,48M):  WQKVT bf16 [6144][4096]  -> after qkv_gemm: WOT bf16 at [0,32M)
  //  [48,64M): Xb bf16 [2048][4096]     (dead after qkv_gemm)
  //  [64,88M): qkv bf16 [2048][6144]    -> ctx at [64,80M) after mid_all
  //  [88,104M): qb  [104,108M): kb  [108,112M): VT [16][128][1024]
  u16* wqkvt = (u16*)ws;
  u16* wot = (u16*)ws;
  u16* xb = (u16*)(ws + 48 * MB);
  u16* qkv = (u16*)(ws + 64 * MB);
  u16* ctx = (u16*)(ws + 64 * MB);
  u16* qb = (u16*)(ws + 88 * MB);
  u16* kb = (u16*)(ws + 104 * MB);
  u16* vt = (u16*)(ws + 108 * MB);

  prep_all<<<dim3(28672), 256, 0, stream>>>(x, wq, wk, wv, xb, wqkvt);
  gemm8p<6, false><<<dim3(256), 512, 0, stream>>>(xb, wqkvt, qkv, 4096, 6144);
  mid_all<<<dim3(38912), 256, 0, stream>>>(wo, qkv, qw, kw, wot, qb, kb, vt);
  flash_attn<<<dim3(1024), 256, 0, stream>>>(qb, kb, vt, ctx);
  gemm8p<4, true><<<dim3(256), 512, 0, stream>>>(ctx, wot, out, 4096, 4096);
}

// Round 3
// 448.702 us; speedup vs baseline: 1.2357x; 1.0305x over previous
//
#include <hip/hip_runtime.h>

// FlashQwenAttention: x@wq/wk/wv -> rmsnorm(q,k) -> rope -> GQA causal attn -> ctx@wo
// B=2 S=1024 H=4096 NH=32 NKV=8 HD=128. Inputs fp32; internal bf16 MFMA.
// R8: pipeline the LDS fragment reads one phase ahead so ds_read port time
// hides under MFMA (R7 was reads->drain->MFMA serial: 1920+1860 cyc/K-tile).
// B-frags for ph0+ph1 read in W0, ph2's in W1, NEXT tile's A-frags in W2
// (ping-ponged reg set). vmcnt ladder re-derived: NP=3 VM(8)@ph1, VM(6)@ph2;
// NP=2 VM(2)@ph0, VM(4)@ph1. Compiler emits counted lgkmcnt for true deps.

#define NH_ 32
#define NKV_ 8
#define HD_ 128
#define SEQ_ 1024
#define HID_ 4096
#define NQKV_ 6144

typedef unsigned short u16;
typedef __bf16 bf16x8 __attribute__((ext_vector_type(8)));
typedef float f32x4 __attribute__((ext_vector_type(4)));

__device__ __forceinline__ u16 f2bf(float f) {
  unsigned int u = __float_as_uint(f);
  return (u16)((u + 0x7FFFu + ((u >> 16) & 1u)) >> 16);
}
__device__ __forceinline__ float bf2f(u16 u) {
  return __uint_as_float(((unsigned int)u) << 16);
}
__device__ __forceinline__ f32x4 mfma16(bf16x8 a, bf16x8 b, f32x4 c) {
  return __builtin_amdgcn_mfma_f32_16x16x32_bf16(a, b, c, 0, 0, 0);
}
__device__ __forceinline__ void gld16(u16* lds, const u16* g) {
  __builtin_amdgcn_global_load_lds(
      (const __attribute__((address_space(1))) unsigned int*)g,
      (__attribute__((address_space(3))) unsigned int*)lds, 16, 0, 0);
}

// ---------------- prep_all: x->bf16 cvt + wq/wk/wv transpose ----------------
__global__ __launch_bounds__(256) void prep_all(
    const float* __restrict__ x, const float* __restrict__ wq,
    const float* __restrict__ wk, const float* __restrict__ wv,
    u16* __restrict__ xb, u16* __restrict__ wqkvt) {
  const int blk = blockIdx.x;
  if (blk < 4096) {
    int i = (blk * 256 + threadIdx.x) * 8;
    float4 a = *(const float4*)(x + i);
    float4 b = *(const float4*)(x + i + 4);
    u16 o[8];
    o[0] = f2bf(a.x); o[1] = f2bf(a.y); o[2] = f2bf(a.z); o[3] = f2bf(a.w);
    o[4] = f2bf(b.x); o[5] = f2bf(b.y); o[6] = f2bf(b.z); o[7] = f2bf(b.w);
    *(uint4*)(xb + i) = *(uint4*)&o[0];
    return;
  }
  __shared__ float t[32][33];
  const int tt = blk - 4096;
  const int k0 = (tt & 127) * 32;
  const int y = tt >> 7;
  const float* src;
  int ldn, n0;
  size_t dofs;
  if (y < 128) { src = wq; ldn = 4096; n0 = y * 32; dofs = 0; }
  else if (y < 160) { src = wk; ldn = 1024; n0 = (y - 128) * 32; dofs = (size_t)4096 * 4096; }
  else { src = wv; ldn = 1024; n0 = (y - 160) * 32; dofs = (size_t)5120 * 4096; }
  const int c = threadIdx.x & 31, r4 = threadIdx.x >> 5;
#pragma unroll
  for (int i = 0; i < 4; ++i) {
    int r = r4 + i * 8;
    t[r][c] = src[(size_t)(k0 + r) * ldn + n0 + c];
  }
  __syncthreads();
#pragma unroll
  for (int i = 0; i < 4; ++i) {
    int r = r4 + i * 8;
    wqkvt[dofs + (size_t)(n0 + r) * HID_ + k0 + c] = f2bf(t[c][r]);
  }
}

// ---------------- mid_all: wo transpose + norm_rope + v_transpose ----------
__global__ __launch_bounds__(256) void mid_all(
    const float* __restrict__ wo, const u16* __restrict__ QKV,
    const float* __restrict__ QW, const float* __restrict__ KW,
    u16* __restrict__ wot, u16* __restrict__ QB, u16* __restrict__ KB,
    u16* __restrict__ VT) {
  const int blk = blockIdx.x;
  if (blk < 16384) {  // wo transpose
    __shared__ float t[32][33];
    const int k0 = (blk & 127) * 32, n0 = (blk >> 7) * 32;
    const int c = threadIdx.x & 31, r4 = threadIdx.x >> 5;
#pragma unroll
    for (int i = 0; i < 4; ++i) {
      int r = r4 + i * 8;
      t[r][c] = wo[(size_t)(k0 + r) * HID_ + n0 + c];
    }
    __syncthreads();
#pragma unroll
    for (int i = 0; i < 4; ++i) {
      int r = r4 + i * 8;
      wot[(size_t)(n0 + r) * HID_ + k0 + c] = f2bf(t[c][r]);
    }
    return;
  }
  if (blk < 36864) {  // norm_rope
    const float QSCALE = 0.08838834764831845f * 1.4426950408889634f;
    int vec = (blk - 16384) * 4 + (threadIdx.x >> 6);
    int lane = threadIdx.x & 63;
    const u16* src;
    u16* dst;
    const float* nw;
    int m;
    float outsc;
    if (vec < 65536) {  // q
      m = vec >> 5;
      int hh = vec & 31;
      src = QKV + (size_t)m * NQKV_ + hh * 128;
      int b = m >> 10, s = m & 1023;
      dst = QB + (size_t)((b * NH_ + hh) * SEQ_ + s) * HD_;
      nw = QW;
      outsc = QSCALE;
    } else {  // k
      int vk = vec - 65536;
      m = vk >> 3;
      int kvh = vk & 7;
      src = QKV + (size_t)m * NQKV_ + 4096 + kvh * 128;
      int b = m >> 10, s = m & 1023;
      dst = KB + (size_t)((b * NKV_ + kvh) * SEQ_ + s) * HD_;
      nw = KW;
      outsc = 1.0f;
    }
    float t1 = bf2f(src[lane]), t2 = bf2f(src[lane + 64]);
    float ss = t1 * t1 + t2 * t2;
#pragma unroll
    for (int off = 32; off >= 1; off >>= 1) ss += __shfl_xor(ss, off);
    float scale = rsqrtf(ss * (1.0f / 128.0f) + 1e-6f) * outsc;
    float n1 = t1 * scale * nw[lane];
    float n2 = t2 * scale * nw[lane + 64];
    int spos = m & 1023;
    float invf = powf(10000.0f, -(float)lane * (1.0f / 64.0f));
    float ang = (float)spos * invf;
    float sn, cs;
    sincosf(ang, &sn, &cs);
    dst[lane] = f2bf(n1 * cs - n2 * sn);
    dst[lane + 64] = f2bf(n1 * sn + n2 * cs);
    return;
  }
  {  // v_transpose
    __shared__ u16 t[32][33];
    const int tt = blk - 36864;
    const int s0 = (tt & 31) * 32, d0 = ((tt >> 5) & 3) * 32;
    const int bkvh = tt >> 7;
    const int b = bkvh >> 3, kvh = bkvh & 7;
    const int c = threadIdx.x & 31, r8 = threadIdx.x >> 5;
#pragma unroll
    for (int i = 0; i < 4; ++i) {
      int r = r8 + i * 8;
      t[r][c] =
          QKV[(size_t)(b * SEQ_ + s0 + r) * NQKV_ + 5120 + kvh * 128 + d0 + c];
    }
    __syncthreads();
#pragma unroll
    for (int i = 0; i < 4; ++i) {
      int r = r8 + i * 8;
      VT[(size_t)(bkvh * HD_ + d0 + r) * SEQ_ + s0 + c] = t[c][r];
    }
  }
}

// ------- pipelined GEMM, BM=128, BN=NF*64: C[M x N] = A[M x K] @ Bt[N x K]^T
// 512 thr = 8 waves (2M x 4N). LDS slot: A 2 lines + B NF lines (line =
// 64 rows x 64 k, 4096 u16, 8 KB; wave w stages bytes [w*1KB, w*1KB+1KB)).
// Swizzle: u16 idx = row*64 + (col ^ ((row&7)<<3)); staged via inverse-
// swizzled global src + linear gld16 dest. Reads pipelined one phase ahead;
// next tile's A read in last window into ping-ponged reg set.

#define BAR() __builtin_amdgcn_s_barrier()
#define PRIO1() __builtin_amdgcn_s_setprio(1)
#define PRIO0() __builtin_amdgcn_s_setprio(0)
#define VM(n) asm volatile("s_waitcnt vmcnt(" #n ")" ::: "memory")

#define STGA(slot, l, koff) \
  gld16(&L[(slot)*SLOT + (l)*4096 + wofs], aB + (size_t)(l)*64*K + (koff))
#define STGB(slot, l, koff) \
  gld16(&L[(slot)*SLOT + 8192 + (l)*4096 + wofs], bB + (size_t)(l)*64*K + (koff))

#define RDB(dst, Ls, p)                                                   \
  dst[0][0] = *(const bf16x8*)&(Ls)[bro + (2*(p))*4096 + acS0];           \
  dst[0][1] = *(const bf16x8*)&(Ls)[bro + (2*(p)+1)*4096 + acS0];         \
  dst[1][0] = *(const bf16x8*)&(Ls)[bro + (2*(p))*4096 + acS1];           \
  dst[1][1] = *(const bf16x8*)&(Ls)[bro + (2*(p)+1)*4096 + acS1];

#define RDA(dst, Ls)                                                      \
  _Pragma("unroll") for (int m_ = 0; m_ < 4; ++m_) {                      \
    dst[0][m_] = *(const bf16x8*)&(Ls)[aro + m_*1024 + acS0];             \
    dst[1][m_] = *(const bf16x8*)&(Ls)[aro + m_*1024 + acS1];             \
  }

#define MMp(p, bq, AF)                                                    \
  _Pragma("unroll") for (int kk = 0; kk < 2; ++kk)                        \
  _Pragma("unroll") for (int m = 0; m < 4; ++m)                           \
  _Pragma("unroll") for (int j = 0; j < 2; ++j)                           \
    acc[m][2*(p)+j] = mfma16(AF[kk][m], bq[kk][j], acc[m][2*(p)+j]);

// steady tile, NP=3 (NF=6)
#define TILE3(SO, SN, AFc, AFn, K1, K2)                                   \
  {                                                                       \
    const u16* Ls = &L[(SO)*SLOT];                                        \
    bf16x8 bq0[2][2], bq1[2][2], bq2[2][2];                               \
    RDB(bq0, Ls, 0); RDB(bq1, Ls, 1);                                     \
    STGB((SN), 4, (K1)); STGB((SN), 5, (K1));                             \
    BAR(); PRIO1(); MMp(0, bq0, AFc); PRIO0(); BAR();                     \
    RDB(bq2, Ls, 2);                                                      \
    STGA((SO), 0, (K2)); STGA((SO), 1, (K2)); STGB((SO), 0, (K2));        \
    BAR(); PRIO1(); MMp(1, bq1, AFc); PRIO0(); VM(8); BAR();              \
    RDA(AFn, (&L[(SN)*SLOT]));                                            \
    STGB((SO), 1, (K2)); STGB((SO), 2, (K2)); STGB((SO), 3, (K2));        \
    BAR(); PRIO1(); MMp(2, bq2, AFc); PRIO0(); VM(6); BAR();              \
  }

// steady tile, NP=2 (NF=4)
#define TILE2(SO, SN, AFc, AFn, K1, K2)                                   \
  {                                                                       \
    const u16* Ls = &L[(SO)*SLOT];                                        \
    bf16x8 bq0[2][2], bq1[2][2];                                          \
    RDB(bq0, Ls, 0); RDB(bq1, Ls, 1);                                     \
    STGB((SN), 2, (K1)); STGB((SN), 3, (K1));                             \
    BAR(); PRIO1(); MMp(0, bq0, AFc); PRIO0(); VM(2); BAR();              \
    RDA(AFn, (&L[(SN)*SLOT]));                                            \
    STGA((SO), 0, (K2)); STGA((SO), 1, (K2));                             \
    STGB((SO), 0, (K2)); STGB((SO), 1, (K2));                             \
    BAR(); PRIO1(); MMp(1, bq1, AFc); PRIO0(); VM(4); BAR();              \
  }

template <int NF, bool F32OUT>
__global__ __launch_bounds__(512, 2) void gemm8p(
    const u16* __restrict__ A_, const u16* __restrict__ Bt,
    void* __restrict__ Cv, const int K, const int ldc) {
  constexpr int NP = NF / 2;
  constexpr int SLOT = (128 + NF * 64) * 64;  // u16 per dbuf slot
  __shared__ __align__(16) u16 L[2 * SLOT];

  // T1: XCD swizzle; grid 256 = 16bm x 16bn, 32 blocks (2 bm rows) per XCD.
  const int sw = (blockIdx.x & 7) * 32 + (blockIdx.x >> 3);
  const int bm = sw >> 4, bn = sw & 15;

  const int tid = threadIdx.x, w = tid >> 6, lane = tid & 63;
  const int wm = w >> 2, wn = w & 3;
  const int ln = lane & 15, quad = lane >> 4;

  // staging source (inverse-swizzled so gld16's linear LDS dest lands right)
  const int srow = lane >> 3;
  const int scol = ((lane & 7) ^ srow) * 8;
  const u16* aB = A_ + (size_t)(bm * 128 + w * 8 + srow) * K + scol;
  const u16* bB = Bt + (size_t)(bn * (NF * 64) + w * 8 + srow) * K + scol;
  const int wofs = w * 512;

  // swizzled fragment read columns
  const int acS0 = (quad * 8) ^ ((ln & 7) << 3);
  const int acS1 = (32 + quad * 8) ^ ((ln & 7) << 3);
  const int aro = (wm * 64 + ln) * 64;
  const int bro = 8192 + (wn * 16 + ln) * 64;

  f32x4 acc[4][NF];
#pragma unroll
  for (int m = 0; m < 4; ++m)
#pragma unroll
    for (int f = 0; f < NF; ++f)
#pragma unroll
      for (int r = 0; r < 4; ++r) acc[m][f][r] = 0.0f;

  const int nt = K >> 6;  // K-tiles, even, >= 4
  bf16x8 af0[2][4], af1[2][4];

  if constexpr (NP == 3) {
    // prologue: t0 full (8), t1 {A01,B0} (3), t1 {B123} (3)
    STGA(0, 0, 0); STGA(0, 1, 0);
    STGB(0, 0, 0); STGB(0, 1, 0); STGB(0, 2, 0);
    STGB(0, 3, 0); STGB(0, 4, 0); STGB(0, 5, 0);
    STGA(1, 0, 64); STGA(1, 1, 64); STGB(1, 0, 64);
    STGB(1, 1, 64); STGB(1, 2, 64); STGB(1, 3, 64);
    VM(6); BAR();
    RDA(af0, (&L[0]));
    int kof = 0;
#pragma unroll 1
    for (int it = 0; it < (nt - 2) / 2; ++it) {
      TILE3(0, 1, af0, af1, kof + 64, kof + 128);
      TILE3(1, 0, af1, af0, kof + 128, kof + 192);
      kof += 128;
    }
    {  // tile nt-2 (slot 0): stage only B45(nt-1); drain
      const u16* Ls = &L[0];
      bf16x8 bq0[2][2], bq1[2][2], bq2[2][2];
      RDB(bq0, Ls, 0); RDB(bq1, Ls, 1);
      STGB(1, 4, kof + 64); STGB(1, 5, kof + 64);
      BAR(); PRIO1(); MMp(0, bq0, af0); PRIO0(); BAR();
      RDB(bq2, Ls, 2);
      BAR(); PRIO1(); MMp(1, bq1, af0); PRIO0(); VM(5); BAR();
      RDA(af1, (&L[SLOT]));
      BAR(); PRIO1(); MMp(2, bq2, af0); PRIO0(); VM(0); BAR();
    }
    {  // tile nt-1 (slot 1): read all, compute
      const u16* Ls = &L[SLOT];
      bf16x8 bq0[2][2], bq1[2][2], bq2[2][2];
      RDB(bq0, Ls, 0); RDB(bq1, Ls, 1); RDB(bq2, Ls, 2);
      BAR();
      PRIO1();
      MMp(0, bq0, af1); MMp(1, bq1, af1); MMp(2, bq2, af1);
      PRIO0();
    }
  } else {
    // prologue: t0 full (6), t1 {A01,B01} (4)
    STGA(0, 0, 0); STGA(0, 1, 0);
    STGB(0, 0, 0); STGB(0, 1, 0); STGB(0, 2, 0); STGB(0, 3, 0);
    STGA(1, 0, 64); STGA(1, 1, 64); STGB(1, 0, 64); STGB(1, 1, 64);
    VM(4); BAR();
    RDA(af0, (&L[0]));
    int kof = 0;
#pragma unroll 1
    for (int it = 0; it < (nt - 2) / 2; ++it) {
      TILE2(0, 1, af0, af1, kof + 64, kof + 128);
      TILE2(1, 0, af1, af0, kof + 128, kof + 192);
      kof += 128;
    }
    {  // tile nt-2 (slot 0)
      const u16* Ls = &L[0];
      bf16x8 bq0[2][2], bq1[2][2];
      RDB(bq0, Ls, 0); RDB(bq1, Ls, 1);
      STGB(1, 2, kof + 64); STGB(1, 3, kof + 64);
      BAR(); PRIO1(); MMp(0, bq0, af0); PRIO0(); VM(2); BAR();
      RDA(af1, (&L[SLOT]));
      BAR(); PRIO1(); MMp(1, bq1, af0); PRIO0(); VM(0); BAR();
    }
    {  // tile nt-1 (slot 1)
      const u16* Ls = &L[SLOT];
      bf16x8 bq0[2][2], bq1[2][2];
      RDB(bq0, Ls, 0); RDB(bq1, Ls, 1);
      BAR();
      PRIO1();
      MMp(0, bq0, af1); MMp(1, bq1, af1);
      PRIO0();
    }
  }

  // ---- epilogue: C write (wave wn owns n-frags g = f*4+wn)
  const int colb = bn * (NF * 64) + wn * 16 + ln;
#pragma unroll
  for (int m = 0; m < 4; ++m) {
#pragma unroll
    for (int r = 0; r < 4; ++r) {
      const int grow = bm * 128 + wm * 64 + m * 16 + quad * 4 + r;
      if (F32OUT) {
        float* dst = (float*)Cv + (size_t)grow * ldc + colb;
#pragma unroll
        for (int f = 0; f < NF; ++f) dst[f * 64] = acc[m][f][r];
      } else {
        u16* dst = (u16*)Cv + (size_t)grow * ldc + colb;
#pragma unroll
        for (int f = 0; f < NF; ++f) dst[f * 64] = f2bf(acc[m][f][r]);
      }
    }
  }
}

#undef TILE3
#undef TILE2
#undef RDB
#undef RDA
#undef MMp
#undef STGA
#undef STGB
#undef BAR
#undef PRIO1
#undef PRIO0
#undef VM

// ---------------- GQA causal flash attention (R3 version) ----------------
__global__ __launch_bounds__(256) void flash_attn(
    const u16* __restrict__ QB, const u16* __restrict__ KB,
    const u16* __restrict__ VT, u16* __restrict__ CTX) {
  __shared__ u16 Ks[4][64][32];   // [kc][key][k-seg]   16 KB
  __shared__ u16 Vs[2][128][32];  // [kchunk][d][key]   16 KB
  __shared__ u16 Pl[4][16][72];   // per-wave P, A-layout, XOR-bit3 swizzle

  const int bid = blockIdx.x;
  const int qt = 15 - (bid >> 6);  // long blocks dispatch first
  const int h = bid & 31, b = (bid >> 5) & 1;
  const int kvh = h >> 2;
  const int tid = threadIdx.x, w = tid >> 6, lane = tid & 63;
  const int ln = lane & 15, quad = lane >> 4;
  const int l4 = lane >> 2, l4r = lane & 3;

  const u16* qbase =
      QB + (size_t)((b * NH_ + h) * SEQ_ + qt * 64 + w * 16 + ln) * HD_;
  bf16x8 qf[4];
#pragma unroll
  for (int kc = 0; kc < 4; ++kc)
    qf[kc] = *(const bf16x8*)(qbase + kc * 32 + quad * 8);

  f32x4 o[8];
#pragma unroll
  for (int t = 0; t < 8; ++t)
#pragma unroll
    for (int r = 0; r < 4; ++r) o[t][r] = 0.0f;
  float m_r[4] = {-3e38f, -3e38f, -3e38f, -3e38f};
  float l_r[4] = {0.0f, 0.0f, 0.0f, 0.0f};

  const u16* krow =
      KB + (size_t)((b * NKV_ + kvh) * SEQ_ + w * 16 + l4) * HD_ + l4r * 8;
  const u16* vrow =
      VT + (size_t)((b * NKV_ + kvh) * HD_ + w * 32 + l4) * SEQ_ + l4r * 8;
  const int pswz = ((ln >> 3) & 1) << 3;

  for (int kt = 0; kt <= qt; ++kt) {
    const int key0 = kt * 64;
#pragma unroll
    for (int i = 0; i < 4; ++i)
      gld16(&Ks[i][w * 16][0], krow + (size_t)key0 * HD_ + i * 32);
#pragma unroll
    for (int i = 0; i < 4; ++i)
      gld16(&Vs[i & 1][w * 32 + (i >> 1) * 16][0],
            vrow + (size_t)(i >> 1) * 16 * SEQ_ + key0 + (i & 1) * 32);
    __syncthreads();

    f32x4 sc[4];
#pragma unroll
    for (int t2 = 0; t2 < 4; ++t2) {
#pragma unroll
      for (int r = 0; r < 4; ++r) sc[t2][r] = 0.0f;
#pragma unroll
      for (int kc = 0; kc < 4; ++kc) {
        bf16x8 kf = *(const bf16x8*)&Ks[kc][t2 * 16 + ln][quad * 8];
        sc[t2] = mfma16(qf[kc], kf, sc[t2]);
      }
    }

    const bool diag = (kt == qt);
    float p[4][4], alpha[4];
#pragma unroll
    for (int r = 0; r < 4; ++r) {
      float s0 = sc[0][r], s1 = sc[1][r], s2 = sc[2][r], s3 = sc[3][r];
      if (diag) {
        const int qi = qt * 64 + w * 16 + quad * 4 + r;
        if (key0 + ln > qi) s0 = -3e38f;
        if (key0 + 16 + ln > qi) s1 = -3e38f;
        if (key0 + 32 + ln > qi) s2 = -3e38f;
        if (key0 + 48 + ln > qi) s3 = -3e38f;
      }
      float mx = fmaxf(fmaxf(s0, s1), fmaxf(s2, s3));
#pragma unroll
      for (int off = 1; off < 16; off <<= 1) mx = fmaxf(mx, __shfl_xor(mx, off));
      float mnew = fmaxf(m_r[r], mx);
      alpha[r] = exp2f(m_r[r] - mnew);
      p[0][r] = exp2f(s0 - mnew);
      p[1][r] = exp2f(s1 - mnew);
      p[2][r] = exp2f(s2 - mnew);
      p[3][r] = exp2f(s3 - mnew);
      float rs = p[0][r] + p[1][r] + p[2][r] + p[3][r];
#pragma unroll
      for (int off = 1; off < 16; off <<= 1) rs += __shfl_xor(rs, off);
      l_r[r] = l_r[r] * alpha[r] + rs;
      m_r[r] = mnew;
    }
#pragma unroll
    for (int t = 0; t < 8; ++t)
#pragma unroll
      for (int r = 0; r < 4; ++r) o[t][r] *= alpha[r];

#pragma unroll
    for (int r = 0; r < 4; ++r) {
      const int row = quad * 4 + r;
      const int wswz = ((row >> 3) & 1) << 3;
#pragma unroll
      for (int t2 = 0; t2 < 4; ++t2)
        Pl[w][row][(t2 * 16 + ln) ^ wswz] = f2bf(p[t2][r]);
    }
    bf16x8 af0 = *(const bf16x8*)&Pl[w][ln][(quad * 8) ^ pswz];
    bf16x8 af1 = *(const bf16x8*)&Pl[w][ln][32 + ((quad * 8) ^ pswz)];
#pragma unroll
    for (int t = 0; t < 8; ++t) {
      bf16x8 vf0 = *(const bf16x8*)&Vs[0][t * 16 + ln][quad * 8];
      o[t] = mfma16(af0, vf0, o[t]);
      bf16x8 vf1 = *(const bf16x8*)&Vs[1][t * 16 + ln][quad * 8];
      o[t] = mfma16(af1, vf1, o[t]);
    }
    __syncthreads();
  }

#pragma unroll
  for (int r = 0; r < 4; ++r) {
    float inv_l = 1.0f / l_r[r];
    int srow = qt * 64 + w * 16 + quad * 4 + r;
    u16* dst = CTX + (size_t)(b * SEQ_ + srow) * (NH_ * HD_) + h * HD_;
#pragma unroll
    for (int t = 0; t < 8; ++t) dst[t * 16 + ln] = f2bf(o[t][r] * inv_l);
  }
}

extern "C" void kernel_launch(void* const* d_in, const int* in_sizes, int n_in,
                              void* d_out, int out_size, void* d_ws,
                              size_t ws_size, hipStream_t stream) {
  const float* x = (const float*)d_in[0];
  const float* wq = (const float*)d_in[1];
  const float* wk = (const float*)d_in[2];
  const float* wv = (const float*)d_in[3];
  const float* wo = (const float*)d_in[4];
  const float* qw = (const float*)d_in[5];
  const float* kw = (const float*)d_in[6];
  float* out = (float*)d_out;
  char* ws = (char*)d_ws;
  const size_t MB = 1024 * 1024;

  //  [0,48M):  WQKVT bf16 [6144][4096]  -> after qkv_gemm: WOT bf16 at [0,32M)
  //  [48,64M): Xb bf16 [2048][4096]     (dead after qkv_gemm)
  //  [64,88M): qkv bf16 [2048][6144]    -> ctx at [64,80M) after mid_all
  //  [88,104M): qb  [104,108M): kb  [108,112M): VT [16][128][1024]
  u16* wqkvt = (u16*)ws;
  u16* wot = (u16*)ws;
  u16* xb = (u16*)(ws + 48 * MB);
  u16* qkv = (u16*)(ws + 64 * MB);
  u16* ctx = (u16*)(ws + 64 * MB);
  u16* qb = (u16*)(ws + 88 * MB);
  u16* kb = (u16*)(ws + 104 * MB);
  u16* vt = (u16*)(ws + 108 * MB);

  prep_all<<<dim3(28672), 256, 0, stream>>>(x, wq, wk, wv, xb, wqkvt);
  gemm8p<6, false><<<dim3(256), 512, 0, stream>>>(xb, wqkvt, qkv, 4096, 6144);
  mid_all<<<dim3(38912), 256, 0, stream>>>(wo, qkv, qw, kw, wot, qb, kb, vt);
  flash_attn<<<dim3(1024), 256, 0, stream>>>(qb, kb, vt, ctx);
  gemm8p<4, true><<<dim3(256), 512, 0, stream>>>(ctx, wot, out, 4096, 4096);
}